// Round 1
// baseline (146.706 us; speedup 1.0000x reference)
//
#include <hip/hip_runtime.h>

// Attr_Tokenizer: for each of N query positions, center on anchor, rotate into
// anchor frame, find nearest point of a fixed ~2821-point integer lattice
// (disk of radius 30), output (index, offset).
//
// Round 1: correctness-first fp64 brute force. One thread per query; grid
// staged in LDS as float2 (uniform broadcast reads in the inner loop).

static constexpr double kHeading = 1.5707963267948966;  // pi/2

__global__ __launch_bounds__(256) void attr_tokenizer_kernel(
    const float2* __restrict__ x,      // [N] as float2
    const float2* __restrict__ y,      // [N] as float2
    const float*  __restrict__ theta,  // [N]
    const float2* __restrict__ grid,   // [G]
    float* __restrict__ out_idx,       // [N]   (index written as float value)
    float* __restrict__ out_off,       // [N,2]
    int n, int g)
{
    extern __shared__ float2 sgrid[];
    for (int i = (int)threadIdx.x; i < g; i += (int)blockDim.x)
        sgrid[i] = grid[i];
    __syncthreads();

    int tid = (int)(blockIdx.x * blockDim.x + threadIdx.x);
    if (tid >= n) return;

    float2 xv = x[tid];
    float2 yv = y[tid];
    double cx = (double)xv.x - (double)yv.x;
    double cy = (double)xv.y - (double)yv.y;
    double phi = -((double)theta[tid] - kHeading);
    double c = cos(phi);
    double s = sin(phi);
    double rx = cx * c - cy * s;
    double ry = cx * s + cy * c;

    double best = 1.0e300;
    int bi = 0;
    #pragma unroll 4
    for (int i = 0; i < g; ++i) {
        float2 gp = sgrid[i];
        double dx = rx - (double)gp.x;
        double dy = ry - (double)gp.y;
        double d2 = fma(dy, dy, dx * dx);
        // strict < keeps the FIRST occurrence of the min (jnp.argmin tie rule)
        if (d2 < best) { best = d2; bi = i; }
    }

    out_idx[tid] = (float)bi;
    float2 gb = sgrid[bi];
    out_off[2 * tid]     = (float)(rx - (double)gb.x);
    out_off[2 * tid + 1] = (float)(ry - (double)gb.y);
}

extern "C" void kernel_launch(void* const* d_in, const int* in_sizes, int n_in,
                              void* d_out, int out_size, void* d_ws, size_t ws_size,
                              hipStream_t stream) {
    const float2* x     = (const float2*)d_in[0];
    const float2* y     = (const float2*)d_in[1];
    const float*  theta = (const float*)d_in[2];
    const float2* grid  = (const float2*)d_in[3];

    int n = in_sizes[2];          // N (theta is [N])
    int g = in_sizes[3] / 2;      // grid is [G,2]

    float* out_idx = (float*)d_out;        // output 0: [N]
    float* out_off = (float*)d_out + n;    // output 1: [N,2]

    int block = 256;
    int blocks = (n + block - 1) / block;
    size_t lds = (size_t)g * sizeof(float2);
    attr_tokenizer_kernel<<<blocks, block, lds, stream>>>(
        x, y, theta, grid, out_idx, out_off, n, g);
}

// Round 2
// 9.914 us; speedup vs baseline: 14.7975x; 14.7975x over previous
//
#include <hip/hip_runtime.h>
#include <math.h>

// Attr_Tokenizer: nearest-grid-token lookup against a fixed integer lattice
// (spacing 1.0) masked to a disk of radius 30, indexed row-major with
// py descending (30..-30) then px ascending (-W..W).
//
// Round 2: analytic per-row argmin. For row k (py = 30-k), the nearest in-row
// lattice point to (rx, ry) is px = clamp(round(rx), -W[k], W[k]) with flat
// index rowstart[k] + px + W[k]. W and rowstart are compile-time constants,
// so a fully-unrolled 61-row scan folds them into immediates: ~11 fp32 VALU
// ops per row, no LDS, no divergence, no fp64.

static constexpr float kHeadingF = 1.57079632679489662f;  // pi/2

struct Tables {
    int   C[61];   // rowstart[k] + W[k]  (so index = C[k] + (int)px)
    float W[61];   // halfwidth of row k
    float PY[61];  // py of row k = 30 - k
};

constexpr Tables make_tables() {
    Tables t{};
    int cum = 0;
    for (int k = 0; k < 61; ++k) {
        int py = 30 - k;
        int w = 0;
        while ((w + 1) * (w + 1) + py * py <= 900) ++w;  // floor(sqrt(900-py^2))
        t.W[k]  = (float)w;
        t.PY[k] = (float)py;
        t.C[k]  = cum + w;
        cum += 2 * w + 1;
    }
    return t;
}

static constexpr Tables T = make_tables();

__global__ __launch_bounds__(256) void attr_tokenizer_kernel(
    const float2* __restrict__ x,      // [N]
    const float2* __restrict__ y,      // [N]
    const float*  __restrict__ theta,  // [N]
    float*  __restrict__ out_idx,      // [N]   (index written as float value)
    float2* __restrict__ out_off,      // [N]
    int n)
{
    int tid = (int)(blockIdx.x * blockDim.x + threadIdx.x);
    if (tid >= n) return;

    float2 xv = x[tid];
    float2 yv = y[tid];
    float cx = xv.x - yv.x;
    float cy = xv.y - yv.y;
    float phi = kHeadingF - theta[tid];      // -(theta - heading)
    float c = __cosf(phi);
    float s = __sinf(phi);
    // use precise sinf/cosf to track the numpy fp32 reference closely
    c = cosf(phi);
    s = sinf(phi);
    float rx = cx * c - cy * s;
    float ry = cx * s + cy * c;

    float pxu = nearbyintf(rx);              // v_rndne_f32; round-half-to-even

    float best = 1.0e30f;
    int   bi = 0;
    float bdx = 0.0f, bdy = 0.0f;

    #pragma unroll
    for (int k = 0; k < 61; ++k) {
        float w  = T.W[k];
        float px = fminf(fmaxf(pxu, -w), w); // clamp to row extent
        float dx = rx - px;
        float dy = ry - T.PY[k];
        float d2 = fmaf(dy, dy, dx * dx);
        int   ii = T.C[k] + (int)px;
        // strict < keeps the earliest (first-occurrence) row on exact ties
        if (d2 < best) { best = d2; bi = ii; bdx = dx; bdy = dy; }
    }

    out_idx[tid] = (float)bi;
    out_off[tid] = make_float2(bdx, bdy);
}

extern "C" void kernel_launch(void* const* d_in, const int* in_sizes, int n_in,
                              void* d_out, int out_size, void* d_ws, size_t ws_size,
                              hipStream_t stream) {
    const float2* x     = (const float2*)d_in[0];
    const float2* y     = (const float2*)d_in[1];
    const float*  theta = (const float*)d_in[2];

    int n = in_sizes[2];                     // N (theta is [N])

    float*  out_idx = (float*)d_out;         // output 0: [N]
    float2* out_off = (float2*)((float*)d_out + n);  // output 1: [N,2]

    int block = 256;
    int blocks = (n + block - 1) / block;
    attr_tokenizer_kernel<<<blocks, block, 0, stream>>>(
        x, y, theta, out_idx, out_off, n);
}

// Round 3
// 9.861 us; speedup vs baseline: 14.8775x; 1.0054x over previous
//
#include <hip/hip_runtime.h>
#include <math.h>

// Attr_Tokenizer: nearest-grid-token lookup against a fixed integer lattice
// (spacing 1.0) masked to a disk of radius 30, indexed row-major with
// py descending (30..-30) then px ascending (-W..W).
//
// Round 3: symmetry-folded exact scan. For ry>0 rows py=-p are strictly
// dominated by +p (equal width -> equal dx, strictly smaller |dy|), so scan
// only 31 rows over ay=|ry|. Tie order vs the reference flat scan:
//   ry>=0: surviving rows in ref order are py descending == our p=30..0 scan,
//          strict '<' keeps first occurrence.
//   ry<0 : surviving rows in ref order are p ascending; scanning p=30..0 with
//          '<=' makes the LAST tie win == smallest p == ref's first occurrence.
// Loop tracks only (best, p); w and the flat row base are recovered in the
// epilogue (w = floor(sqrt(900-p^2)) is exact in fp32; base from a 61-entry
// __constant__ table).

static constexpr float kHeadingF = 1.57079632679489662f;  // pi/2

struct RowTab {
    int base[61];   // rowstart[k] + W[k]  (flat index = base[k] + px)
};

constexpr RowTab make_rowtab() {
    RowTab t{};
    int cum = 0;
    for (int k = 0; k < 61; ++k) {
        int py = 30 - k;
        int w = 0;
        while ((w + 1) * (w + 1) + py * py <= 900) ++w;
        t.base[k] = cum + w;
        cum += 2 * w + 1;
    }
    return t;
}

__constant__ RowTab kTab = make_rowtab();

struct WTab { float w[31]; };
constexpr WTab make_wtab() {
    WTab t{};
    for (int p = 0; p <= 30; ++p) {
        int w = 0;
        while ((w + 1) * (w + 1) + p * p <= 900) ++w;
        t.w[p] = (float)w;
    }
    return t;
}
static constexpr WTab W = make_wtab();   // compile-time only (folded literals)

__global__ __launch_bounds__(256) void attr_tokenizer_kernel(
    const float2* __restrict__ x,      // [N]
    const float2* __restrict__ y,      // [N]
    const float*  __restrict__ theta,  // [N]
    float*  __restrict__ out_idx,      // [N]   (index written as float value)
    float2* __restrict__ out_off,      // [N]
    int n)
{
    int tid = (int)(blockIdx.x * blockDim.x + threadIdx.x);
    if (tid >= n) return;

    float2 xv = x[tid];
    float2 yv = y[tid];
    float cx = xv.x - yv.x;
    float cy = xv.y - yv.y;
    float phi = kHeadingF - theta[tid];      // -(theta - heading)
    float s, c;
    sincosf(phi, &s, &c);
    float rx = cx * c - cy * s;
    float ry = cx * s + cy * c;

    float pxu = nearbyintf(rx);              // v_rndne_f32
    float ay  = fabsf(ry);
    bool  neg = ry < 0.0f;

    float best = 1.0e30f;
    int   bp   = 0;

    #pragma unroll
    for (int p = 30; p >= 0; --p) {
        float w  = W.w[p];                   // compile-time literal
        float px = fminf(fmaxf(pxu, -w), w);
        float dx = rx - px;
        float dy = ay - (float)p;
        float d2 = fmaf(dx, dx, dy * dy);
        bool take = neg ? (d2 <= best) : (d2 < best);
        if (take) { best = d2; bp = p; }
    }

    float bpf = (float)bp;
    float w   = floorf(sqrtf(fmaf(-bpf, bpf, 900.0f)));  // exact for p=0..30
    float px  = fminf(fmaxf(pxu, -w), w);
    int   ipx = (int)px;
    int   kref = neg ? 30 + bp : 30 - bp;
    int   ii  = kTab.base[kref] + ipx;
    float pyb = neg ? -bpf : bpf;

    out_idx[tid] = (float)ii;
    out_off[tid] = make_float2(rx - px, ry - pyb);
}

extern "C" void kernel_launch(void* const* d_in, const int* in_sizes, int n_in,
                              void* d_out, int out_size, void* d_ws, size_t ws_size,
                              hipStream_t stream) {
    const float2* x     = (const float2*)d_in[0];
    const float2* y     = (const float2*)d_in[1];
    const float*  theta = (const float*)d_in[2];

    int n = in_sizes[2];                     // N (theta is [N])

    float*  out_idx = (float*)d_out;         // output 0: [N]
    float2* out_off = (float2*)((float*)d_out + n);  // output 1: [N,2]

    int block = 256;
    int blocks = (n + block - 1) / block;
    attr_tokenizer_kernel<<<blocks, block, 0, stream>>>(
        x, y, theta, out_idx, out_off, n);
}